// Round 4
// baseline (182.787 us; speedup 1.0000x reference)
//
#include <hip/hip_runtime.h>
#include <hip/hip_bf16.h>
#include <stdint.h>

typedef __attribute__((ext_vector_type(8))) short short8;
typedef __attribute__((ext_vector_type(4))) float f32x4;

#define MFMA16(a, b, c) __builtin_amdgcn_mfma_f32_16x16x32_bf16(a, b, c, 0, 0, 0)

__device__ __forceinline__ unsigned short f2bf_u(float f) {
  union { float f; uint32_t u; } x; x.f = f;
  uint32_t r = (x.u + 0x7fffu + ((x.u >> 16) & 1u)) >> 16;
  return (unsigned short)r;
}
__device__ __forceinline__ short f2bf(float f) { return (short)f2bf_u(f); }

__device__ __forceinline__ uint32_t pack_bf2(float lo, float hi) {
  __hip_bfloat162 h = __float22bfloat162_rn(make_float2(lo, hi));  // v_cvt_pk_bf16_f32
  union { __hip_bfloat162 h; uint32_t u; } c; c.h = h;
  return c.u;
}

// async global->LDS, 16B per lane. dest = wave-uniform base + lane*16.
__device__ __forceinline__ void gload_lds16(const void* g, void* lds) {
  __builtin_amdgcn_global_load_lds(
      (const __attribute__((address_space(1))) uint32_t*)(uintptr_t)g,
      (__attribute__((address_space(3))) uint32_t*)(uintptr_t)lds,
      16, 0, 0);
}

// ---------------- fp32 -> bf16 elementwise convert (X) ----------------
__global__ __launch_bounds__(256) void convert_bf16_kernel(
    const float* __restrict__ in, short* __restrict__ out, int n4) {
  int i = blockIdx.x * 256 + threadIdx.x;
  if (i >= n4) return;
  float4 v = reinterpret_cast<const float4*>(in)[i];
  short4 o;
  o.x = f2bf(v.x); o.y = f2bf(v.y); o.z = f2bf(v.z); o.w = f2bf(v.w);
  reinterpret_cast<short4*>(out)[i] = o;
}

// ------------- W (K x N fp32) -> WT (N x K bf16) tiled transpose -------------
__global__ __launch_bounds__(256) void transpose_conv_kernel(
    const float* __restrict__ in, short* __restrict__ out, int K, int N) {
  __shared__ float tile[32][33];
  int k0 = blockIdx.x * 32, n0 = blockIdx.y * 32;
  int tx = threadIdx.x, ty = threadIdx.y;  // (32,8)
#pragma unroll
  for (int i = 0; i < 4; ++i)
    tile[ty + 8 * i][tx] = in[(size_t)(k0 + ty + 8 * i) * N + n0 + tx];
  __syncthreads();
#pragma unroll
  for (int i = 0; i < 4; ++i)
    out[(size_t)(n0 + ty + 8 * i) * K + k0 + tx] = f2bf(tile[tx][ty + 8 * i]);
}

// ---------------- bf16 GEMM: C(MxN fp32) = A(MxK) * BT(NxK)^T ----------------
__global__ __launch_bounds__(256) void gemm_bf16(
    const short* __restrict__ A, const short* __restrict__ BT,
    float* __restrict__ C, int M, int N, int K) {
  __shared__ short As[128 * 32];
  __shared__ short Bs[128 * 32];
  int m0 = blockIdx.x * 128, n0 = blockIdx.y * 128;
  int t = threadIdx.x;
  int w = t >> 6, lane = t & 63;
  int wr = w >> 1, wc = w & 1;
  int lr = lane & 15, lg = lane >> 4;

  f32x4 acc[4][4] = {};

  for (int k0 = 0; k0 < K; k0 += 32) {
    __syncthreads();
#pragma unroll
    for (int i = 0; i < 2; ++i) {
      int c = t + 256 * i;
      int row = c >> 2;
      int colb = (c & 3) * 8;
      gload_lds16(A + (size_t)(m0 + row) * K + k0 + colb, &As[c * 8]);
      gload_lds16(BT + (size_t)(n0 + row) * K + k0 + colb, &Bs[c * 8]);
    }
    __syncthreads();
    short8 af[4], bf[4];
#pragma unroll
    for (int mi = 0; mi < 4; ++mi)
      af[mi] = *(const short8*)&As[(wr * 64 + mi * 16 + lr) * 32 + lg * 8];
#pragma unroll
    for (int ni = 0; ni < 4; ++ni)
      bf[ni] = *(const short8*)&Bs[(wc * 64 + ni * 16 + lr) * 32 + lg * 8];
#pragma unroll
    for (int mi = 0; mi < 4; ++mi)
#pragma unroll
      for (int ni = 0; ni < 4; ++ni)
        acc[mi][ni] = MFMA16(af[mi], bf[ni], acc[mi][ni]);
  }
#pragma unroll
  for (int mi = 0; mi < 4; ++mi)
#pragma unroll
    for (int ni = 0; ni < 4; ++ni) {
      int row = m0 + wr * 64 + mi * 16 + lg * 4;
      int col = n0 + wc * 64 + ni * 16 + lr;
#pragma unroll
      for (int r = 0; r < 4; ++r)
        C[(size_t)(row + r) * N + col] = acc[mi][ni][r];
    }
}

// ------------- RMSNorm + 2D RoPE + layout transform -------------
__global__ __launch_bounds__(256) void normrope_kernel(
    const float* __restrict__ QKV, const float* __restrict__ qg,
    const float* __restrict__ kg, const int* __restrict__ pos,
    short* __restrict__ Qp, short* __restrict__ Kp, short* __restrict__ Vt) {
  int wid = (blockIdx.x * 256 + threadIdx.x) >> 6;
  int lane = threadIdx.x & 63;
  int t = wid >> 5;      // token 0..4095
  int hh = wid & 31;     // 0-15 q, 16-23 k, 24-31 v
  int b = t >> 10, s = t & 1023;
  int col = (hh < 16) ? hh * 64 : (hh < 24) ? 1024 + (hh - 16) * 64 : 1536 + (hh - 24) * 64;
  float x = QKV[(size_t)t * 2048 + col + lane];
  float ss = x * x;
#pragma unroll
  for (int o = 1; o < 64; o <<= 1) ss += __shfl_xor(ss, o);
  float v = x * rsqrtf(ss * (1.0f / 64.0f) + 1e-6f);
  if (hh < 16) v *= 1.0f + qg[lane];
  else if (hh < 24) v *= 1.0f + kg[lane];
  if (hh < 24) {
    int fi = lane & 15;
    float p = (float)((lane < 32) ? pos[t * 2] : pos[t * 2 + 1]);
    // inv_freq = 10000^(-fi/16) = exp2(-fi * log2(10000)/16)
    float ang = p * exp2f((float)fi * -0.8304820237218405f);
    float sn, cs;
    __sincosf(ang, &sn, &cs);
    float partner = __shfl_xor(v, 16);
    v = ((lane & 31) < 16) ? (v * cs - partner * sn) : (v * cs + partner * sn);
  }
  short o = f2bf(v);
  if (hh < 16)      Qp[((size_t)((b * 16 + hh) * 1024 + s)) * 64 + lane] = o;
  else if (hh < 24) Kp[((size_t)((b * 8 + (hh - 16)) * 1024 + s)) * 64 + lane] = o;
  else              Vt[((size_t)((b * 8 + (hh - 24)) * 64 + lane)) * 1024 + s] = o;
}

// ------------- attention v3: no-max softmax, 4-way split-KV, K prefetch -------------
// grid: 2048 blocks = B*H*(S/32); 4 waves = 4 kv quarters of one 32-q tile.
// Wave w: q rows qt0..qt0+32, kv w*256..+256 in 8 steps of 32.
// No running max (logits bounded ~|44| after rms-norm); partials merged via LDS.
__global__ __launch_bounds__(256) void attn_kernel(
    const short* __restrict__ Qp, const short* __restrict__ Kp,
    const short* __restrict__ Vt, short* __restrict__ attn) {
  __shared__ float red[3][2][4][16][16];  // [w-1][mi][db][lr][lg*4+r]
  __shared__ float lred[3][2][16];        // [w-1][mi][lr]
  int blk = blockIdx.x;
  int qb = blk & 31;
  int h = (blk >> 5) & 15;
  int b = blk >> 9;
  int hk = h >> 1;
  int w = threadIdx.x >> 6, lane = threadIdx.x & 63;
  int lr = lane & 15, lg = lane >> 4;
  int qt0 = qb * 32;

  const short* Qb = Qp + ((size_t)(b * 16 + h) * 1024) * 64;
  const short* Kb = Kp + ((size_t)(b * 8 + hk) * 1024) * 64 + (size_t)w * 256 * 64;
  const short* Vb = Vt + ((size_t)(b * 8 + hk) * 64) * 1024 + w * 256;

  short8 qf[2][2];
#pragma unroll
  for (int mi = 0; mi < 2; ++mi)
#pragma unroll
    for (int f = 0; f < 2; ++f)
      qf[mi][f] = *(const short8*)&Qb[(qt0 + mi * 16 + lr) * 64 + f * 32 + lg * 8];

  f32x4 acc[2][4] = {};   // [mi][db]: out^T[d=db*16+lg*4+r][q=qt0+mi*16+lr]
  float lsum[2] = {0.0f, 0.0f};

  short8 ka[4], kb_[4], vv[4];
#pragma unroll
  for (int kvb = 0; kvb < 2; ++kvb)
#pragma unroll
    for (int f = 0; f < 2; ++f)
      ka[kvb * 2 + f] = *(const short8*)&Kb[(kvb * 16 + lr) * 64 + f * 32 + lg * 8];

  auto body = [&](int it, short8* cur, short8* nxt) {
    int kvo = it * 32;
    // V loads: issue early, consumed at the end of the body
#pragma unroll
    for (int db = 0; db < 4; ++db)
      vv[db] = *(const short8*)&Vb[(size_t)(db * 16 + lr) * 1024 + kvo + lg * 8];
    // K prefetch for next iteration
    int kvn = ((it + 1 < 8) ? it + 1 : 7) * 32;
#pragma unroll
    for (int kvb = 0; kvb < 2; ++kvb)
#pragma unroll
      for (int f = 0; f < 2; ++f)
        nxt[kvb * 2 + f] = *(const short8*)&Kb[(kvn + kvb * 16 + lr) * 64 + f * 32 + lg * 8];
    // S^T = K * Q^T (registers only)
    f32x4 sv[2][2];
#pragma unroll
    for (int mi = 0; mi < 2; ++mi)
#pragma unroll
      for (int kvb = 0; kvb < 2; ++kvb) {
        f32x4 s = {};
        s = MFMA16(cur[kvb * 2 + 0], qf[mi][0], s);
        s = MFMA16(cur[kvb * 2 + 1], qf[mi][1], s);
        sv[mi][kvb] = s;
      }
#pragma unroll
    for (int mi = 0; mi < 2; ++mi) {
      float p[2][4];
#pragma unroll
      for (int kvb = 0; kvb < 2; ++kvb)
#pragma unroll
        for (int r = 0; r < 4; ++r) {
          p[kvb][r] = __expf(sv[mi][kvb][r]);
          lsum[mi] += p[kvb][r];
        }
      uint32_t pk[2][2];
#pragma unroll
      for (int kvb = 0; kvb < 2; ++kvb)
#pragma unroll
        for (int wd = 0; wd < 2; ++wd)
          pk[kvb][wd] = pack_bf2(p[kvb][2 * wd], p[kvb][2 * wd + 1]);
      union { uint32_t u[4]; short8 s; } pb;
#pragma unroll
      for (int j2 = 0; j2 < 4; ++j2) {
        int src = (2 * (lg & 1) + (j2 >> 1)) * 16 + lr;
        uint32_t lo = (uint32_t)__shfl((int)pk[0][j2 & 1], src);
        uint32_t hi = (uint32_t)__shfl((int)pk[1][j2 & 1], src);
        pb.u[j2] = (lg >= 2) ? hi : lo;
      }
#pragma unroll
      for (int db = 0; db < 4; ++db)
        acc[mi][db] = MFMA16(vv[db], pb.s, acc[mi][db]);
    }
  };

#pragma unroll
  for (int it2 = 0; it2 < 8; it2 += 2) {
    body(it2, ka, kb_);
    body(it2 + 1, kb_, ka);
  }

  // ---- epilogue: reduce lsum over lg, merge 4 kv quarters, write ----
#pragma unroll
  for (int mi = 0; mi < 2; ++mi) {
    lsum[mi] += __shfl_xor(lsum[mi], 16);
    lsum[mi] += __shfl_xor(lsum[mi], 32);
  }
  if (w > 0) {
#pragma unroll
    for (int mi = 0; mi < 2; ++mi) {
#pragma unroll
      for (int db = 0; db < 4; ++db)
        *(f32x4*)&red[w - 1][mi][db][lr][lg * 4] = acc[mi][db];
      if (lg == 0) lred[w - 1][mi][lr] = lsum[mi];
    }
  }
  __syncthreads();
  if (w == 0) {
#pragma unroll
    for (int mi = 0; mi < 2; ++mi) {
      float lt = lsum[mi] + lred[0][mi][lr] + lred[1][mi][lr] + lred[2][mi][lr];
      float inv = 1.0f / lt;
      size_t rowbase = ((size_t)(b * 1024 + qt0 + mi * 16 + lr)) * 1024 + h * 64;
#pragma unroll
      for (int db = 0; db < 4; ++db) {
        f32x4 o = acc[mi][db];
#pragma unroll
        for (int s2 = 0; s2 < 3; ++s2)
          o += *(const f32x4*)&red[s2][mi][db][lr][lg * 4];
        uint32_t w0 = pack_bf2(o[0] * inv, o[1] * inv);
        uint32_t w1 = pack_bf2(o[2] * inv, o[3] * inv);
        uint32_t* pp = (uint32_t*)&attn[rowbase + db * 16 + lg * 4];
        pp[0] = w0;
        pp[1] = w1;
      }
    }
  }
}

extern "C" void kernel_launch(void* const* d_in, const int* in_sizes, int n_in,
                              void* d_out, int out_size, void* d_ws, size_t ws_size,
                              hipStream_t stream) {
  const float* X  = (const float*)d_in[0];
  const float* Wq = (const float*)d_in[1];
  const float* Wk = (const float*)d_in[2];
  const float* Wv = (const float*)d_in[3];
  const float* Wo = (const float*)d_in[4];
  const float* qg = (const float*)d_in[5];
  const float* kg = (const float*)d_in[6];
  const int* pos  = (const int*)d_in[7];
  float* out = (float*)d_out;

  char* ws = (char*)d_ws;
  short* XB    = (short*)(ws);                       // 8 MB  X bf16
  short* WTQKV = (short*)(ws + ((size_t)8 << 20));   // 4 MB  [Wq^T;Wk^T;Wv^T]
  short* WOT   = (short*)(ws + ((size_t)12 << 20));  // 2 MB  Wo^T
  float* QKV   = (float*)(ws + ((size_t)14 << 20));  // 32 MB (4096x2048 fp32)
  short* QP    = (short*)(ws + ((size_t)46 << 20));  // 8 MB
  short* KP    = (short*)(ws + ((size_t)54 << 20));  // 4 MB
  short* VT    = (short*)(ws + ((size_t)58 << 20));  // 4 MB
  short* ATT   = (short*)(ws + ((size_t)62 << 20));  // 8 MB

  convert_bf16_kernel<<<4096, 256, 0, stream>>>(X, XB, 1048576);
  dim3 tb(32, 8);
  transpose_conv_kernel<<<dim3(32, 32), tb, 0, stream>>>(Wq, WTQKV, 1024, 1024);
  transpose_conv_kernel<<<dim3(32, 16), tb, 0, stream>>>(Wk, WTQKV + (size_t)1024 * 1024, 1024, 512);
  transpose_conv_kernel<<<dim3(32, 16), tb, 0, stream>>>(Wv, WTQKV + (size_t)1536 * 1024, 1024, 512);
  transpose_conv_kernel<<<dim3(32, 32), tb, 0, stream>>>(Wo, WOT, 1024, 1024);

  gemm_bf16<<<dim3(32, 16), 256, 0, stream>>>(XB, WTQKV, QKV, 4096, 2048, 1024);
  normrope_kernel<<<32768, 256, 0, stream>>>(QKV, qg, kg, pos, QP, KP, VT);
  attn_kernel<<<2048, 256, 0, stream>>>(QP, KP, VT, ATT);
  gemm_bf16<<<dim3(32, 8), 256, 0, stream>>>(ATT, WOT, out, 4096, 1024, 1024);
}

// Round 5
// 174.693 us; speedup vs baseline: 1.0463x; 1.0463x over previous
//
#include <hip/hip_runtime.h>
#include <hip/hip_bf16.h>
#include <stdint.h>

typedef __attribute__((ext_vector_type(8))) short short8;
typedef __attribute__((ext_vector_type(4))) float f32x4;

#define MFMA16(a, b, c) __builtin_amdgcn_mfma_f32_16x16x32_bf16(a, b, c, 0, 0, 0)

__device__ __forceinline__ unsigned short f2bf_u(float f) {
  union { float f; uint32_t u; } x; x.f = f;
  uint32_t r = (x.u + 0x7fffu + ((x.u >> 16) & 1u)) >> 16;
  return (unsigned short)r;
}
__device__ __forceinline__ short f2bf(float f) { return (short)f2bf_u(f); }

__device__ __forceinline__ uint32_t pack_bf2(float lo, float hi) {
  __hip_bfloat162 h = __float22bfloat162_rn(make_float2(lo, hi));  // v_cvt_pk_bf16_f32
  union { __hip_bfloat162 h; uint32_t u; } c; c.h = h;
  return c.u;
}

// async global->LDS, 16B per lane. dest = wave-uniform base + lane*16.
__device__ __forceinline__ void gload_lds16(const void* g, void* lds) {
  __builtin_amdgcn_global_load_lds(
      (const __attribute__((address_space(1))) uint32_t*)(uintptr_t)g,
      (__attribute__((address_space(3))) uint32_t*)(uintptr_t)lds,
      16, 0, 0);
}

// ---------------- fp32 -> bf16 elementwise convert (X) ----------------
__global__ __launch_bounds__(256) void convert_bf16_kernel(
    const float* __restrict__ in, short* __restrict__ out, int n4) {
  int i = blockIdx.x * 256 + threadIdx.x;
  if (i >= n4) return;
  float4 v = reinterpret_cast<const float4*>(in)[i];
  short4 o;
  o.x = f2bf(v.x); o.y = f2bf(v.y); o.z = f2bf(v.z); o.w = f2bf(v.w);
  reinterpret_cast<short4*>(out)[i] = o;
}

// ------- all W (K x N fp32) -> WT (N x K bf16), one launch, grid (32,96) -------
__global__ __launch_bounds__(256) void transpose_all_kernel(
    const float* __restrict__ Wq, const float* __restrict__ Wk,
    const float* __restrict__ Wv, const float* __restrict__ Wo,
    short* __restrict__ WTQKV, short* __restrict__ WOT) {
  __shared__ float tile[32][33];
  int yb = blockIdx.y;
  const float* src; short* dst; int N; int yy;
  if (yb < 32)      { src = Wq; dst = WTQKV;                       N = 1024; yy = yb; }
  else if (yb < 48) { src = Wk; dst = WTQKV + (size_t)1024 * 1024; N = 512;  yy = yb - 32; }
  else if (yb < 64) { src = Wv; dst = WTQKV + (size_t)1536 * 1024; N = 512;  yy = yb - 48; }
  else              { src = Wo; dst = WOT;                         N = 1024; yy = yb - 64; }
  int k0 = blockIdx.x * 32, n0 = yy * 32;
  int tx = threadIdx.x, ty = threadIdx.y;  // (32,8)
#pragma unroll
  for (int i = 0; i < 4; ++i)
    tile[ty + 8 * i][tx] = src[(size_t)(k0 + ty + 8 * i) * N + n0 + tx];
  __syncthreads();
#pragma unroll
  for (int i = 0; i < 4; ++i)
    dst[(size_t)(n0 + ty + 8 * i) * 1024 + k0 + tx] = f2bf(tile[tx][ty + 8 * i]);
}

// ---------------- bf16 GEMM: C(MxN fp32) = A(MxK) * BT(NxK)^T ----------------
// 128x128 tile, BK=32, 4 waves (each 64x64), m97-style 2-barrier loop.
__global__ __launch_bounds__(256) void gemm_bf16(
    const short* __restrict__ A, const short* __restrict__ BT,
    float* __restrict__ C, int M, int N, int K) {
  __shared__ short As[128 * 32];
  __shared__ short Bs[128 * 32];
  int m0 = blockIdx.x * 128, n0 = blockIdx.y * 128;
  int t = threadIdx.x;
  int w = t >> 6, lane = t & 63;
  int wr = w >> 1, wc = w & 1;
  int lr = lane & 15, lg = lane >> 4;

  f32x4 acc[4][4] = {};

  for (int k0 = 0; k0 < K; k0 += 32) {
    __syncthreads();
#pragma unroll
    for (int i = 0; i < 2; ++i) {
      int c = t + 256 * i;
      gload_lds16(A + (size_t)(m0 + (c >> 2)) * K + k0 + (c & 3) * 8, &As[c * 8]);
      gload_lds16(BT + (size_t)(n0 + (c >> 2)) * K + k0 + (c & 3) * 8, &Bs[c * 8]);
    }
    __syncthreads();
    short8 af[4], bf[4];
#pragma unroll
    for (int mi = 0; mi < 4; ++mi)
      af[mi] = *(const short8*)&As[(wr * 64 + mi * 16 + lr) * 32 + lg * 8];
#pragma unroll
    for (int ni = 0; ni < 4; ++ni)
      bf[ni] = *(const short8*)&Bs[(wc * 64 + ni * 16 + lr) * 32 + lg * 8];
    __builtin_amdgcn_s_setprio(1);
#pragma unroll
    for (int mi = 0; mi < 4; ++mi)
#pragma unroll
      for (int ni = 0; ni < 4; ++ni)
        acc[mi][ni] = MFMA16(af[mi], bf[ni], acc[mi][ni]);
    __builtin_amdgcn_s_setprio(0);
  }
#pragma unroll
  for (int mi = 0; mi < 4; ++mi)
#pragma unroll
    for (int ni = 0; ni < 4; ++ni) {
      int row = m0 + wr * 64 + mi * 16 + lg * 4;
      int col = n0 + wc * 64 + ni * 16 + lr;
#pragma unroll
      for (int r = 0; r < 4; ++r)
        C[(size_t)(row + r) * N + col] = acc[mi][ni][r];
    }
}

// ---------------- 128x64-tile GEMM variant (for narrow N / more blocks) ----------------
// 4 waves, each 32x64 (acc 2x4). Same BK=32 2-barrier loop.
__global__ __launch_bounds__(256) void gemm_bf16_bn64(
    const short* __restrict__ A, const short* __restrict__ BT,
    float* __restrict__ C, int M, int N, int K) {
  __shared__ short As[128 * 32];
  __shared__ short Bs[64 * 32];
  int m0 = blockIdx.x * 128, n0 = blockIdx.y * 64;
  int t = threadIdx.x;
  int w = t >> 6, lane = t & 63;
  int lr = lane & 15, lg = lane >> 4;

  f32x4 acc[2][4] = {};

  for (int k0 = 0; k0 < K; k0 += 32) {
    __syncthreads();
#pragma unroll
    for (int i = 0; i < 2; ++i) {
      int c = t + 256 * i;
      gload_lds16(A + (size_t)(m0 + (c >> 2)) * K + k0 + (c & 3) * 8, &As[c * 8]);
    }
    gload_lds16(BT + (size_t)(n0 + (t >> 2)) * K + k0 + (t & 3) * 8, &Bs[t * 8]);
    __syncthreads();
    short8 af[2], bf[4];
#pragma unroll
    for (int mi = 0; mi < 2; ++mi)
      af[mi] = *(const short8*)&As[(w * 32 + mi * 16 + lr) * 32 + lg * 8];
#pragma unroll
    for (int ni = 0; ni < 4; ++ni)
      bf[ni] = *(const short8*)&Bs[(ni * 16 + lr) * 32 + lg * 8];
    __builtin_amdgcn_s_setprio(1);
#pragma unroll
    for (int mi = 0; mi < 2; ++mi)
#pragma unroll
      for (int ni = 0; ni < 4; ++ni)
        acc[mi][ni] = MFMA16(af[mi], bf[ni], acc[mi][ni]);
    __builtin_amdgcn_s_setprio(0);
  }
#pragma unroll
  for (int mi = 0; mi < 2; ++mi)
#pragma unroll
    for (int ni = 0; ni < 4; ++ni) {
      int row = m0 + w * 32 + mi * 16 + lg * 4;
      int col = n0 + ni * 16 + lr;
#pragma unroll
      for (int r = 0; r < 4; ++r)
        C[(size_t)(row + r) * N + col] = acc[mi][ni][r];
    }
}

// ------------- RMSNorm + 2D RoPE + layout transform -------------
__global__ __launch_bounds__(256) void normrope_kernel(
    const float* __restrict__ QKV, const float* __restrict__ qg,
    const float* __restrict__ kg, const int* __restrict__ pos,
    short* __restrict__ Qp, short* __restrict__ Kp, short* __restrict__ Vt) {
  int wid = (blockIdx.x * 256 + threadIdx.x) >> 6;
  int lane = threadIdx.x & 63;
  int t = wid >> 5;      // token 0..4095
  int hh = wid & 31;     // 0-15 q, 16-23 k, 24-31 v
  int b = t >> 10, s = t & 1023;
  int col = (hh < 16) ? hh * 64 : (hh < 24) ? 1024 + (hh - 16) * 64 : 1536 + (hh - 24) * 64;
  float x = QKV[(size_t)t * 2048 + col + lane];
  float ss = x * x;
#pragma unroll
  for (int o = 1; o < 64; o <<= 1) ss += __shfl_xor(ss, o);
  float v = x * rsqrtf(ss * (1.0f / 64.0f) + 1e-6f);
  if (hh < 16) v *= 1.0f + qg[lane];
  else if (hh < 24) v *= 1.0f + kg[lane];
  if (hh < 24) {
    int fi = lane & 15;
    float p = (float)((lane < 32) ? pos[t * 2] : pos[t * 2 + 1]);
    float ang = p * exp2f((float)fi * -0.8304820237218405f);
    float sn, cs;
    __sincosf(ang, &sn, &cs);
    float partner = __shfl_xor(v, 16);
    v = ((lane & 31) < 16) ? (v * cs - partner * sn) : (v * cs + partner * sn);
  }
  short o = f2bf(v);
  if (hh < 16)      Qp[((size_t)((b * 16 + hh) * 1024 + s)) * 64 + lane] = o;
  else if (hh < 24) Kp[((size_t)((b * 8 + (hh - 16)) * 1024 + s)) * 64 + lane] = o;
  else              Vt[((size_t)((b * 8 + (hh - 24)) * 64 + lane)) * 1024 + s] = o;
}

// ------------- attention v4: XCD-locality remap + no-max softmax + split-KV -------------
// 2048 blocks. Remap so all 32 q-blocks of one (b,h) land on ONE XCD (xcd = hwid%8):
// KV (256KB/group) stays L2-resident -> loads are L2 hits, prefetch covers latency.
__global__ __launch_bounds__(256) void attn_kernel(
    const short* __restrict__ Qp, const short* __restrict__ Kp,
    const short* __restrict__ Vt, short* __restrict__ attn) {
  __shared__ float red[3][2][4][16][16];  // [w-1][mi][db][lr][lg*4+r]
  __shared__ float lred[3][2][16];        // [w-1][mi][lr]
  int wg = blockIdx.x;
  int xcd = wg & 7, slot = wg >> 3;          // hw: xcd = wg % 8
  int group = xcd * 8 + (slot >> 5);         // 0..63 = (b,h); 8 groups per xcd
  int qb = slot & 31;
  int b = group >> 4, h = group & 15;
  int hk = h >> 1;
  int w = threadIdx.x >> 6, lane = threadIdx.x & 63;
  int lr = lane & 15, lg = lane >> 4;
  int qt0 = qb * 32;

  const short* Qb = Qp + ((size_t)(b * 16 + h) * 1024) * 64;
  const short* Kb = Kp + ((size_t)(b * 8 + hk) * 1024) * 64 + (size_t)w * 256 * 64;
  const short* Vb = Vt + ((size_t)(b * 8 + hk) * 64) * 1024 + w * 256;

  short8 qf[2][2];
#pragma unroll
  for (int mi = 0; mi < 2; ++mi)
#pragma unroll
    for (int f = 0; f < 2; ++f)
      qf[mi][f] = *(const short8*)&Qb[(qt0 + mi * 16 + lr) * 64 + f * 32 + lg * 8];

  f32x4 acc[2][4] = {};   // [mi][db]: out^T[d=db*16+lg*4+r][q=qt0+mi*16+lr]
  float lsum[2] = {0.0f, 0.0f};

  short8 ka[4], kb_[4], vv[4];
#pragma unroll
  for (int kvb = 0; kvb < 2; ++kvb)
#pragma unroll
    for (int f = 0; f < 2; ++f)
      ka[kvb * 2 + f] = *(const short8*)&Kb[(kvb * 16 + lr) * 64 + f * 32 + lg * 8];

  auto body = [&](int it, short8* cur, short8* nxt) {
    int kvo = it * 32;
    // V loads: issue early, consumed at the end of the body
#pragma unroll
    for (int db = 0; db < 4; ++db)
      vv[db] = *(const short8*)&Vb[(size_t)(db * 16 + lr) * 1024 + kvo + lg * 8];
    // K prefetch for next iteration
    int kvn = ((it + 1 < 8) ? it + 1 : 7) * 32;
#pragma unroll
    for (int kvb = 0; kvb < 2; ++kvb)
#pragma unroll
      for (int f = 0; f < 2; ++f)
        nxt[kvb * 2 + f] = *(const short8*)&Kb[(kvn + kvb * 16 + lr) * 64 + f * 32 + lg * 8];
    // S^T = K * Q^T (registers only)
    f32x4 sv[2][2];
    __builtin_amdgcn_s_setprio(1);
#pragma unroll
    for (int mi = 0; mi < 2; ++mi)
#pragma unroll
      for (int kvb = 0; kvb < 2; ++kvb) {
        f32x4 s = {};
        s = MFMA16(cur[kvb * 2 + 0], qf[mi][0], s);
        s = MFMA16(cur[kvb * 2 + 1], qf[mi][1], s);
        sv[mi][kvb] = s;
      }
    __builtin_amdgcn_s_setprio(0);
#pragma unroll
    for (int mi = 0; mi < 2; ++mi) {
      float p[2][4];
#pragma unroll
      for (int kvb = 0; kvb < 2; ++kvb)
#pragma unroll
        for (int r = 0; r < 4; ++r) {
          p[kvb][r] = __expf(sv[mi][kvb][r]);
          lsum[mi] += p[kvb][r];
        }
      uint32_t pk[2][2];
#pragma unroll
      for (int kvb = 0; kvb < 2; ++kvb)
#pragma unroll
        for (int wd = 0; wd < 2; ++wd)
          pk[kvb][wd] = pack_bf2(p[kvb][2 * wd], p[kvb][2 * wd + 1]);
      union { uint32_t u[4]; short8 s; } pb;
#pragma unroll
      for (int j2 = 0; j2 < 4; ++j2) {
        int src = (2 * (lg & 1) + (j2 >> 1)) * 16 + lr;
        uint32_t lo = (uint32_t)__shfl((int)pk[0][j2 & 1], src);
        uint32_t hi = (uint32_t)__shfl((int)pk[1][j2 & 1], src);
        pb.u[j2] = (lg >= 2) ? hi : lo;
      }
      __builtin_amdgcn_s_setprio(1);
#pragma unroll
      for (int db = 0; db < 4; ++db)
        acc[mi][db] = MFMA16(vv[db], pb.s, acc[mi][db]);
      __builtin_amdgcn_s_setprio(0);
    }
  };

#pragma unroll
  for (int it2 = 0; it2 < 8; it2 += 2) {
    body(it2, ka, kb_);
    body(it2 + 1, kb_, ka);
  }

  // ---- epilogue: reduce lsum over lg, merge 4 kv quarters, write ----
#pragma unroll
  for (int mi = 0; mi < 2; ++mi) {
    lsum[mi] += __shfl_xor(lsum[mi], 16);
    lsum[mi] += __shfl_xor(lsum[mi], 32);
  }
  if (w > 0) {
#pragma unroll
    for (int mi = 0; mi < 2; ++mi) {
#pragma unroll
      for (int db = 0; db < 4; ++db)
        *(f32x4*)&red[w - 1][mi][db][lr][lg * 4] = acc[mi][db];
      if (lg == 0) lred[w - 1][mi][lr] = lsum[mi];
    }
  }
  __syncthreads();
  if (w == 0) {
#pragma unroll
    for (int mi = 0; mi < 2; ++mi) {
      float lt = lsum[mi] + lred[0][mi][lr] + lred[1][mi][lr] + lred[2][mi][lr];
      float inv = 1.0f / lt;
      size_t rowbase = ((size_t)(b * 1024 + qt0 + mi * 16 + lr)) * 1024 + h * 64;
#pragma unroll
      for (int db = 0; db < 4; ++db) {
        f32x4 o = acc[mi][db];
#pragma unroll
        for (int s2 = 0; s2 < 3; ++s2)
          o += *(const f32x4*)&red[s2][mi][db][lr][lg * 4];
        uint32_t w0 = pack_bf2(o[0] * inv, o[1] * inv);
        uint32_t w1 = pack_bf2(o[2] * inv, o[3] * inv);
        uint32_t* pp = (uint32_t*)&attn[rowbase + db * 16 + lg * 4];
        pp[0] = w0;
        pp[1] = w1;
      }
    }
  }
}

extern "C" void kernel_launch(void* const* d_in, const int* in_sizes, int n_in,
                              void* d_out, int out_size, void* d_ws, size_t ws_size,
                              hipStream_t stream) {
  const float* X  = (const float*)d_in[0];
  const float* Wq = (const float*)d_in[1];
  const float* Wk = (const float*)d_in[2];
  const float* Wv = (const float*)d_in[3];
  const float* Wo = (const float*)d_in[4];
  const float* qg = (const float*)d_in[5];
  const float* kg = (const float*)d_in[6];
  const int* pos  = (const int*)d_in[7];
  float* out = (float*)d_out;

  char* ws = (char*)d_ws;
  short* XB    = (short*)(ws);                       // 8 MB  X bf16
  short* WTQKV = (short*)(ws + ((size_t)8 << 20));   // 4 MB  [Wq^T;Wk^T;Wv^T]
  short* WOT   = (short*)(ws + ((size_t)12 << 20));  // 2 MB  Wo^T
  float* QKV   = (float*)(ws + ((size_t)14 << 20));  // 32 MB (4096x2048 fp32)
  short* QP    = (short*)(ws + ((size_t)46 << 20));  // 8 MB
  short* KP    = (short*)(ws + ((size_t)54 << 20));  // 4 MB
  short* VT    = (short*)(ws + ((size_t)58 << 20));  // 4 MB
  short* ATT   = (short*)(ws + ((size_t)62 << 20));  // 8 MB

  convert_bf16_kernel<<<4096, 256, 0, stream>>>(X, XB, 1048576);
  transpose_all_kernel<<<dim3(32, 96), dim3(32, 8), 0, stream>>>(Wq, Wk, Wv, Wo, WTQKV, WOT);

  gemm_bf16<<<dim3(32, 16), 256, 0, stream>>>(XB, WTQKV, QKV, 4096, 2048, 1024);
  normrope_kernel<<<32768, 256, 0, stream>>>(QKV, qg, kg, pos, QP, KP, VT);
  attn_kernel<<<2048, 256, 0, stream>>>(QP, KP, VT, ATT);
  gemm_bf16_bn64<<<dim3(32, 16), 256, 0, stream>>>(ATT, WOT, out, 4096, 1024, 1024);
}